// Round 7
// baseline (309.114 us; speedup 1.0000x reference)
//
#include <hip/hip_runtime.h>

#define N_ 256
#define D_ 64
#define C_ 32
#define R_ 16
#define O_ 32

typedef _Float16 half8 __attribute__((ext_vector_type(8)));
typedef _Float16 half4 __attribute__((ext_vector_type(4)));
typedef float f32x16 __attribute__((ext_vector_type(16)));

// Kernel 1: left/right prep. UNCHANGED (isolate this round's variables).
__global__ __launch_bounds__(256) void prep_kernel(
    const float* __restrict__ left, const float* __restrict__ right,
    _Float16* __restrict__ lw, _Float16* __restrict__ rw,
    float* __restrict__ msum) {
  const int b = blockIdx.x, t = threadIdx.x;
  const int n = ((b >> 3) << 1) | (t >> 7);
  const int d = ((b & 7) << 3) | ((t >> 4) & 7);
  const int r = t & 15;
  const size_t sbase = ((size_t)(n * D_ + d) * C_) * R_ + r;
  const size_t dbase = (size_t)((d * R_ + r) * N_ + n) * C_;

  float lmx = -1e30f, rmx = -1e30f;
  {
    float vals[C_];
#pragma unroll
    for (int i = 0; i < C_; i++) {
      float v = left[sbase + (size_t)i * R_];
      vals[i] = v;
      lmx = fmaxf(lmx, v);
    }
    half8 pk[4];
#pragma unroll
    for (int i = 0; i < C_; i++) pk[i >> 3][i & 7] = (_Float16)__expf(vals[i] - lmx);
    half8* dst = (half8*)(lw + dbase);
#pragma unroll
    for (int q = 0; q < 4; q++) dst[q] = pk[q];
  }
  {
    float vals[C_];
#pragma unroll
    for (int i = 0; i < C_; i++) {
      float v = right[sbase + (size_t)i * R_];
      vals[i] = v;
      rmx = fmaxf(rmx, v);
    }
    half8 pk[4];
#pragma unroll
    for (int i = 0; i < C_; i++) pk[i >> 3][i & 7] = (_Float16)__expf(vals[i] - rmx);
    half8* dst = (half8*)(rw + dbase);
#pragma unroll
    for (int q = 0; q < 4; q++) dst[q] = pk[q];
  }
  msum[(d * R_ + r) * N_ + n] = lmx + rmx;
}

// Kernel 2 v3: one block (512 thr = 8 waves) per (d,r), two-half K pipeline.
// Coalesced o-slice loads (R4, verified). Chunk k (k*64+l float4s into the
// (oa,r) slice) holds quad (oa, i = 8k + (l>>3), j = 4*(l&7)..+3).
// Half = k&1 (= i-bit3): half0 = chunks {0,2} (i in 0..7,16..23), half1 = {1,3}.
// s_loc = ((l>>3)<<2)|((l&7)>>1), slot = (k>>1)<<5 | oa,
// byte = (s_loc<<10 | slot<<4 | (l&1)<<3) ^ ((s_loc&7)<<4)  [swizzle both sides].
// Pipeline: load{0,2} -> exp/store half0 -> bar -> prefetch{1,3} ->
// GEMM half0 -> bar -> exp/store half1 -> bar -> GEMM half1 -> epilogue.
// LDS 32KB + ~1.2KB; launch_bounds(512,6) -> 3 blocks/CU.
__global__ __launch_bounds__(512, 6) void main_kernel(
    const float* __restrict__ logits, const _Float16* lw, const _Float16* rw,
    const float* __restrict__ msum, _Float16* scrA, _Float16* scrB) {
  __shared__ __align__(16) _Float16 Wl[32 * 64 * 8];  // 32 KB (one K-half)
  __shared__ float psum_o[32];
  __shared__ float msum_s[N_];

  const int bid = blockIdx.x;
  const int workid = ((bid & 7) << 7) | (bid >> 3);  // XCD chunking
  const int d = workid >> 4, r = workid & 15;

  const int t = threadIdx.x;
  const int w = t >> 6, l = t & 63;
  const int o = l & 31, jb = l >> 5;

  // ---- GEMM A-side fragments (register-resident before any scr write) ----
  const _Float16* lbase = lw + (size_t)((d * R_ + r) * N_) * C_;
  const _Float16* rbase = rw + (size_t)((d * R_ + r) * N_) * C_;
  const int row = (w << 5) | o;
  const half8* lp = (const half8*)(lbase + row * C_ + (jb << 4));
  const half8 LhA = lp[0];
  const half8 LhB = lp[1];
  const half8* rp2 = (const half8*)(rbase + row * C_);
  half8 Rh[4];
#pragma unroll
  for (int q = 0; q < 4; q++) Rh[q] = rp2[q];

  if (t < N_) msum_s[t] = msum[(d * R_ + r) * N_ + t];

  const float4* lg4 =
      (const float4*)(logits + ((size_t)((d * O_ + (w << 2)) * R_ + r) << 10));
  const int s_loc = ((l >> 3) << 2) | ((l & 7) >> 1);
  const int wbase = (s_loc << 10) | ((l & 1) << 3);
  const int wxor = (s_loc & 7) << 4;

  float lsum[4] = {0.f, 0.f, 0.f, 0.f};

  // ---- load half0 chunks (k = 2*kk in {0,2}) ----
  float4 v[4][2];
#pragma unroll
  for (int sl = 0; sl < 4; sl++) {
#pragma unroll
    for (int kk = 0; kk < 2; kk++)
      v[sl][kk] = lg4[(sl << 12) + ((kk << 1) << 6) + l];  // k*64 + l, k=2kk
  }

  // ---- exp + store half 0 ----
#pragma unroll
  for (int sl = 0; sl < 4; sl++) {
    const int oa = (w << 2) | sl;
#pragma unroll
    for (int kk = 0; kk < 2; kk++) {
      const float4 f = v[sl][kk];
      const float e0 = __expf(f.x), e1 = __expf(f.y), e2 = __expf(f.z),
                  e3 = __expf(f.w);
      lsum[sl] += (e0 + e1) + (e2 + e3);
      half4 hq = {(_Float16)e0, (_Float16)e1, (_Float16)e2, (_Float16)e3};
      const int slot_ = (kk << 5) | oa;  // i>>4 = kk for k = 2kk
      *(half4*)((char*)Wl + ((wbase | (slot_ << 4)) ^ wxor)) = hq;
    }
  }
  __syncthreads();  // (1) Wl half-0 ready

  // ---- prefetch half1 chunks (k = 2*kk+1 in {1,3}) — in flight under GEMM0 ----
#pragma unroll
  for (int sl = 0; sl < 4; sl++) {
#pragma unroll
    for (int kk = 0; kk < 2; kk++)
      v[sl][kk] = lg4[(sl << 12) + (((kk << 1) | 1) << 6) + l];
  }

  f32x16 acc;
#pragma unroll
  for (int g = 0; g < 16; g++) acc[g] = 0.f;

  // ---- GEMM half 0: i-octet = s>>2 in [0,8) ----
#pragma unroll
  for (int s = 0; s < 32; s++) {
    const half8 Bf =
        *(const half8*)((const char*)Wl + (((s << 10) | (l << 4)) ^ ((s & 7) << 4)));
    const _Float16 Lsc = LhA[s >> 2];
    const half8 Ld = {Lsc, Lsc, Lsc, Lsc, Lsc, Lsc, Lsc, Lsc};
    acc = __builtin_amdgcn_mfma_f32_32x32x16_f16(Ld * Rh[s & 3], Bf, acc, 0, 0, 0);
  }
  __syncthreads();  // (2) done reading half-0; prefetches drained

  // ---- exp + store half 1 ----
#pragma unroll
  for (int sl = 0; sl < 4; sl++) {
    const int oa = (w << 2) | sl;
#pragma unroll
    for (int kk = 0; kk < 2; kk++) {
      const float4 f = v[sl][kk];
      const float e0 = __expf(f.x), e1 = __expf(f.y), e2 = __expf(f.z),
                  e3 = __expf(f.w);
      lsum[sl] += (e0 + e1) + (e2 + e3);
      half4 hq = {(_Float16)e0, (_Float16)e1, (_Float16)e2, (_Float16)e3};
      const int slot_ = (kk << 5) | oa;
      *(half4*)((char*)Wl + ((wbase | (slot_ << 4)) ^ wxor)) = hq;
    }
  }
  // per-slice wave reduction -> softmax denominators (full row now summed)
#pragma unroll
  for (int sl = 0; sl < 4; sl++) {
    float ss = lsum[sl];
#pragma unroll
    for (int off = 32; off >= 1; off >>= 1) ss += __shfl_xor(ss, off);
    if (l == 0) psum_o[(w << 2) | sl] = ss;
  }
  __syncthreads();  // (3) Wl half-1 + psum ready

  // ---- GEMM half 1: i-octet = 8 + (s>>2) ----
#pragma unroll
  for (int s = 0; s < 32; s++) {
    const half8 Bf =
        *(const half8*)((const char*)Wl + (((s << 10) | (l << 4)) ^ ((s & 7) << 4)));
    const _Float16 Lsc = LhB[s >> 2];
    const half8 Ld = {Lsc, Lsc, Lsc, Lsc, Lsc, Lsc, Lsc, Lsc};
    acc = __builtin_amdgcn_mfma_f32_32x32x16_f16(Ld * Rh[s & 3], Bf, acc, 0, 0, 0);
  }

  const float rlogsum = __logf(psum_o[o]);

  // ---- Epilogue: fp16 coalesced store to (d,r,n,o) scratch (overlaid lw/rw;
  //      byte region (d*R+r)*16KB == this block's lw slice -> block-exclusive) ----
  _Float16* sb = ((w < 4) ? scrA : scrB) + ((size_t)(d * R_ + r) << 13) +
                 ((w & 3) << 10) + o;
#pragma unroll
  for (int g = 0; g < 16; g++) {
    const int rowt = (g & 3) + ((g >> 2) << 3) + (jb << 2);
    const int n = (w << 5) | rowt;
    const float val = __logf(acc[g]) - rlogsum + msum_s[n];
    sb[rowt << 5] = (_Float16)val;
  }
}

// Kernel 3: transpose fp16 (d,r,n,o) -> fp32 out (n,d,o,r), stride-20 LDS tile.
__global__ __launch_bounds__(256) void trans_kernel(const _Float16* scrA,
                                                    const _Float16* scrB,
                                                    float* __restrict__ out) {
  __shared__ float tile[8 * 32 * 20];  // [nl][o] rows of 20 (16 r + pad)
  const int bid = blockIdx.x;
  const int d = bid >> 5, chunk = bid & 31;
  const int n0 = chunk << 3;
  const _Float16* src = (chunk < 16) ? scrA : scrB;
  const int t = threadIdx.x;

  {
    const int r_t = t >> 4, i16 = t & 15;
    const _Float16* rb =
        src + ((size_t)(d * R_ + r_t) << 13) + ((chunk & 15) << 8);
#pragma unroll
    for (int k = 0; k < 4; k++) {
      const int f = (k << 4) | i16;
      const half4 v = *(const half4*)(rb + (f << 2));
      const int nl = f >> 3, o4 = (f & 7) << 2;
#pragma unroll
      for (int j = 0; j < 4; j++)
        tile[((nl << 5) | (o4 + j)) * 20 + r_t] = (float)v[j];
    }
  }
  __syncthreads();
  {
    const int n_w = t >> 5, pos = t & 31;
    float* ob = out + (((size_t)(n0 + n_w) * D_ + d) << 9);
#pragma unroll
    for (int k = 0; k < 4; k++) {
      const int idx = (k << 5) | pos;
      const float4 v =
          *(const float4*)&tile[((n_w << 5) | (idx >> 2)) * 20 + ((pos & 3) << 2)];
      *(float4*)(ob + (idx << 2)) = v;
    }
  }
}

extern "C" void kernel_launch(void* const* d_in, const int* in_sizes, int n_in,
                              void* d_out, int out_size, void* d_ws, size_t ws_size,
                              hipStream_t stream) {
  const float* left = (const float*)d_in[0];
  const float* right = (const float*)d_in[1];
  const float* logits = (const float*)d_in[2];
  float* out = (float*)d_out;
  _Float16* lw = (_Float16*)d_ws;                                        // 16 MB
  _Float16* rw = (_Float16*)((char*)d_ws + (size_t)16 * 1024 * 1024);    // 16 MB
  float* ms = (float*)((char*)d_ws + (size_t)32 * 1024 * 1024);          // 1 MB
  _Float16* scrA = (_Float16*)d_ws;  // overlays lw (per-(d,r) exclusive)
  _Float16* scrB = (_Float16*)((char*)d_ws + (size_t)16 * 1024 * 1024);

  prep_kernel<<<1024, 256, 0, stream>>>(left, right, lw, rw, ms);
  main_kernel<<<1024, 512, 0, stream>>>(logits, lw, rw, ms, scrA, scrB);
  trans_kernel<<<2048, 256, 0, stream>>>(scrA, scrB, out);
}